// Round 13
// baseline (55.116 us; speedup 1.0000x reference)
//
#include <hip/hip_runtime.h>
#include <hip/hip_bf16.h>
#include <math.h>

typedef __bf16 bf16;
typedef __attribute__((ext_vector_type(4))) __bf16 bf16x4;
typedef __attribute__((ext_vector_type(8))) __bf16 bf16x8;
typedef __attribute__((ext_vector_type(4))) float f32x4;

#define T_DIM 1024
#define C_DIM 256
#define HEADS 8

// Pre-swizzled tile images: rows of 64 bf16 (128B), XOR-swizzled on 16B
// granules (harmless for direct-global fragment reads; conflict-free for the
// LDS paths that still use it).
static __device__ __forceinline__ int tb(int row, int col) {
  return row * 128 + ((((col >> 3) ^ row) & 7) << 4) + ((col & 7) << 1);
}

// ---------------- kernel 0: prep ----------------
__global__ __launch_bounds__(256) void k_prep(const float* __restrict__ x,
    const float* __restrict__ Wq, const float* __restrict__ Wkv, const float* __restrict__ Wo,
    char* __restrict__ xTt, char* __restrict__ Wbt, char* __restrict__ Wot) {
  const int tid = threadIdx.x;
  const int b = blockIdx.x;
  if (b < 512) {
    __shared__ float tile[64][65];
    const int n = b >> 6, rem = b & 63, tt64 = rem >> 2, ct = (rem & 3) << 6;
    const float* xp = x + ((size_t)n * C_DIM + ct) * T_DIM + tt64 * 64;
    const int t4 = (tid & 15) * 4, c0 = tid >> 4;
#pragma unroll
    for (int i = 0; i < 4; ++i) {
      const int c = c0 + i * 16;
      float4 v = *(const float4*)(xp + (size_t)c * T_DIM + t4);
      tile[c][t4] = v.x; tile[c][t4 + 1] = v.y; tile[c][t4 + 2] = v.z; tile[c][t4 + 3] = v.w;
    }
    __syncthreads();
    char* dst = xTt + (((size_t)(n * 8 + (tt64 >> 1))) * 4 + (rem & 3)) * 16384;
    const int rbase = (tt64 & 1) * 64;
#pragma unroll
    for (int i = 0; i < 2; ++i) {
      const int idx = tid + i * 256;
      const int tl = idx >> 3, c8 = (idx & 7) * 8;
      bf16x8 v;
#pragma unroll
      for (int j = 0; j < 8; ++j) v[j] = (bf16)tile[c8 + j][tl];
      *(bf16x8*)(dst + tb(rbase + tl, c8)) = v;
    }
  } else {
    const bool isWo = (b >= 532);
    const int o0 = (b - (isWo ? 532 : 512)) * 64;
#pragma unroll
    for (int i = 0; i < 8; ++i) {
      const int idx = tid + i * 256;
      const int row = idx >> 5, c8 = (idx & 31) * 8;
      const int o = o0 + row;
      const float* src = isWo ? (Wo + (size_t)o * C_DIM + c8)
                              : (o < 512 ? Wq + (size_t)o * C_DIM + c8
                                         : Wkv + (size_t)(o - 512) * C_DIM + c8);
      float4 a = *(const float4*)src;
      float4 bq4 = *(const float4*)(src + 4);
      bf16x8 v;
      v[0]=(bf16)a.x; v[1]=(bf16)a.y; v[2]=(bf16)a.z; v[3]=(bf16)a.w;
      v[4]=(bf16)bq4.x; v[5]=(bf16)bq4.y; v[6]=(bf16)bq4.z; v[7]=(bf16)bq4.w;
      char* base = isWo ? Wot : Wbt;
      char* dst = base + (((size_t)(o >> 7)) * 4 + (c8 >> 6)) * 16384;
      *(bf16x8*)(dst + tb(o & 127, c8 & 63)) = v;
    }
  }
}

// ---------------- kernel 1: QKV projection (128x128, BK=64, T14 reg-staged) ----------------
__global__ __launch_bounds__(256) void k_qkv(const char* __restrict__ Wbt, const char* __restrict__ xTt,
    const float* __restrict__ bq, const float* __restrict__ bkv,
    bf16* __restrict__ q_ws, char* __restrict__ Kt, char* __restrict__ Vt) {
  __shared__ __attribute__((aligned(128))) unsigned char smem[34816];
  const int tid = threadIdx.x;
  const int nt = blockIdx.x, mt = blockIdx.y, n = blockIdx.z;
  const int w = tid >> 6, lane = tid & 63, lrow = lane & 15, lg = lane >> 4;
  const int wm = (w >> 1) * 64, wn = (w & 1) * 64;
  const char* gA = Wbt + (size_t)mt * 65536;
  const char* gB = xTt + ((size_t)(n * 8 + nt)) * 65536;
  const float s2 = 0.18033688f;   // 0.125 * log2(e)
  const int coff = w * 1024 + lane * 16;

  bf16x8 sA0, sA1, sA2, sA3, sB0, sB1, sB2, sB3;
  auto issue = [&](int kk) {
    const char* a = gA + kk * 16384 + coff;
    sA0 = *(const bf16x8*)(a);         sA1 = *(const bf16x8*)(a + 4096);
    sA2 = *(const bf16x8*)(a + 8192);  sA3 = *(const bf16x8*)(a + 12288);
    const char* bsrc = gB + kk * 16384 + coff;
    sB0 = *(const bf16x8*)(bsrc);        sB1 = *(const bf16x8*)(bsrc + 4096);
    sB2 = *(const bf16x8*)(bsrc + 8192); sB3 = *(const bf16x8*)(bsrc + 12288);
  };

  f32x4 acc[4][4] = {};
  issue(0);
#pragma unroll 1
  for (int kk = 0; kk < 4; ++kk) {
    __syncthreads();                       // prev iter LDS reads done (WAR)
    char* da = (char*)smem + coff;
    *(bf16x8*)(da)         = sA0; *(bf16x8*)(da + 4096)  = sA1;
    *(bf16x8*)(da + 8192)  = sA2; *(bf16x8*)(da + 12288) = sA3;
    char* db = (char*)smem + 16384 + coff;
    *(bf16x8*)(db)         = sB0; *(bf16x8*)(db + 4096)  = sB1;
    *(bf16x8*)(db + 8192)  = sB2; *(bf16x8*)(db + 12288) = sB3;
    if (kk < 3) issue(kk + 1);             // latency hides under this iter's MFMA
    __syncthreads();                       // writes visible
    const char* As = (const char*)smem;
    const char* Bs = As + 16384;
    bf16x8 af[4][2], bv[4][2];
#pragma unroll
    for (int mi = 0; mi < 4; ++mi)
#pragma unroll
      for (int kh = 0; kh < 2; ++kh)
        af[mi][kh] = *(const bf16x8*)(As + tb(wm + mi * 16 + lrow, kh * 32 + lg * 8));
#pragma unroll
    for (int ni = 0; ni < 4; ++ni)
#pragma unroll
      for (int kh = 0; kh < 2; ++kh)
        bv[ni][kh] = *(const bf16x8*)(Bs + tb(wn + ni * 16 + lrow, kh * 32 + lg * 8));
#pragma unroll
    for (int kh = 0; kh < 2; ++kh)
#pragma unroll
      for (int mi = 0; mi < 4; ++mi)
#pragma unroll
        for (int ni = 0; ni < 4; ++ni)
          acc[mi][ni] = __builtin_amdgcn_mfma_f32_16x16x32_bf16(af[mi][kh], bv[ni][kh], acc[mi][ni], 0, 0, 0);
  }
  __syncthreads();                         // compute done before epilogue LDS reuse

  const int obase = mt * 128 + wm + lg * 4;
  const int tcol0 = nt * 128 + wn + lrow;
  if (mt < 8) {
#pragma unroll
    for (int mi = 0; mi < 4; ++mi) {
      const int o = obase + mi * 16;
      if (mt < 4) {                      // Q (pre-scaled by s2) -> q_ws[nh][t][64]
        const float4 bb = *(const float4*)(bq + o);
        const int nh = n * 8 + (o >> 6), d = o & 63;
        bf16* qrow = q_ws + (size_t)nh * (T_DIM * 64) + d;
#pragma unroll
        for (int ni = 0; ni < 4; ++ni) {
          const int t = tcol0 + ni * 16;
          f32x4 v = acc[mi][ni];
          bf16x4 pk;
          pk[0]=(bf16)((v[0]+bb.x)*s2); pk[1]=(bf16)((v[1]+bb.y)*s2);
          pk[2]=(bf16)((v[2]+bb.z)*s2); pk[3]=(bf16)((v[3]+bb.w)*s2);
          *(bf16x4*)(qrow + (size_t)t * 64) = pk;
        }
      } else {                           // K -> Kt swizzled tiles [nh][st][64x64]
        const int o2 = o - 512;
        const float4 bb = *(const float4*)(bkv + o2);
        const int nh = n * 8 + (o2 >> 6), d = o2 & 63;
        char* tbase = Kt + (size_t)nh * 16 * 8192;
#pragma unroll
        for (int ni = 0; ni < 4; ++ni) {
          const int t = tcol0 + ni * 16;
          f32x4 v = acc[mi][ni];
          bf16x4 pk;
          pk[0]=(bf16)(v[0]+bb.x); pk[1]=(bf16)(v[1]+bb.y); pk[2]=(bf16)(v[2]+bb.z); pk[3]=(bf16)(v[3]+bb.w);
          *(bf16x4*)(tbase + (t >> 6) * 8192 + tb(t & 63, d)) = pk;
        }
      }
    }
  } else {
    // V route: acc -> LDS [128][132] (+bias), then 16B granule stores into Vt.
    bf16* tp = (bf16*)smem;
#pragma unroll
    for (int mi = 0; mi < 4; ++mi) {
      const int o3g = (mt - 8) * 128 + wm + mi * 16 + lg * 4;
      const float4 bb = *(const float4*)(bkv + 512 + o3g);
      const float* bbp = (const float*)&bb;
      const int o3l = wm + mi * 16 + lg * 4;
#pragma unroll
      for (int ni = 0; ni < 4; ++ni) {
        const int tl = wn + ni * 16 + lrow;
        f32x4 v = acc[mi][ni];
#pragma unroll
        for (int r = 0; r < 4; ++r)
          tp[(o3l + r) * 132 + tl] = (bf16)(v[r] + bbp[r]);
      }
    }
    __syncthreads();
    const int row = tid >> 1, half = tid & 1;
    const int o3 = (mt - 8) * 128 + row;
    const int nh = n * 8 + (o3 >> 5), dv = o3 & 31;
    char* tile = Vt + (size_t)nh * 16 * 4096 + (nt * 2 + half) * 4096;
    const bf16* src = tp + row * 132 + half * 64;
#pragma unroll
    for (int g = 0; g < 8; ++g) {
      bf16x4 lo = *(const bf16x4*)(src + g * 8);
      bf16x4 hi = *(const bf16x4*)(src + g * 8 + 4);
      bf16x8 vv;
      vv[0]=lo[0]; vv[1]=lo[1]; vv[2]=lo[2]; vv[3]=lo[3];
      vv[4]=hi[0]; vv[5]=hi[1]; vv[6]=hi[2]; vv[7]=hi[3];
      *(bf16x8*)(tile + tb(dv, g * 8)) = vv;
    }
  }
}

// ---------------- kernel 2: causal attention (ZERO-STAGING: K/V direct from L2) ----------------
// K/V per head = 192 KB, L2-resident (guide m169: staging L2-fit data is pure
// overhead). Fragments read directly from the pre-swizzled global tiles via
// tb() offsets. Paired Q-tiles (qt0=qp, qt1=15-qp): K/V fragment registers are
// REUSED by both states (halves L2 traffic, balances CU slots). LDS = per-wave
// P round-trip only (8 KB); same-wave ds ordering -> NO barriers in the kernel.
__global__ __launch_bounds__(256) void k_attn(const bf16* __restrict__ q_ws,
    const char* __restrict__ Kt, const char* __restrict__ Vt, char* __restrict__ attTt) {
  __shared__ __attribute__((aligned(128))) unsigned char smem[16384]; // 4 waves x (pwB 2K | pwA 2K)
  const int tid = threadIdx.x;
  const int nh = blockIdx.x, qp = blockIdx.y;
  const int w = tid >> 6, lane = tid & 63, lrow = lane & 15, lg = lane >> 4;
  const int tl = w * 16 + lrow;
  const char* Ktb = Kt + (size_t)nh * 16 * 8192;
  const char* Vtb = Vt + (size_t)nh * 16 * 4096;
  const int n = nh >> 3, h = nh & 7;

  const int qt0 = qp, qt1 = 15 - qp;   // qt0 <= 7 < 8 <= qt1
  const int tg0 = qt0 * 64 + tl, tg1 = qt1 * 64 + tl;
  const bf16* qb0 = q_ws + ((size_t)nh * T_DIM + tg0) * 64;
  const bf16* qb1 = q_ws + ((size_t)nh * T_DIM + tg1) * 64;
  const bf16x8 qA0 = *(const bf16x8*)(qb0 + lg * 8);
  const bf16x8 qA1 = *(const bf16x8*)(qb0 + 32 + lg * 8);
  const bf16x8 qB0 = *(const bf16x8*)(qb1 + lg * 8);
  const bf16x8 qB1 = *(const bf16x8*)(qb1 + 32 + lg * 8);

  char* pwB = (char*)smem + w * 4096;
  char* pwA = pwB + 2048;

  float l0 = 0.f, l1 = 0.f;
  f32x4 o0a = {}, o0b = {}, o1a = {}, o1b = {};

  // exp + tree-sum + pack + P-write for one state
  auto smfin = [&](const f32x4* sacc, float& l, char* pws, bool diag) {
    float p[16];
#pragma unroll
    for (int rt = 0; rt < 4; ++rt)
#pragma unroll
      for (int r = 0; r < 4; ++r) {
        float e = __builtin_amdgcn_exp2f(sacc[rt][r]);
        if (diag && (rt * 16 + lg * 4 + r) > tl) e = 0.f;
        p[rt * 4 + r] = e;
      }
    float t0 = (p[0] + p[1]) + (p[2] + p[3]);
    float t1 = (p[4] + p[5]) + (p[6] + p[7]);
    float t2 = (p[8] + p[9]) + (p[10] + p[11]);
    float t3 = (p[12] + p[13]) + (p[14] + p[15]);
    float ps = (t0 + t1) + (t2 + t3);
    ps += __shfl_xor(ps, 16);
    ps += __shfl_xor(ps, 32);
    l += ps;
#pragma unroll
    for (int rt = 0; rt < 4; ++rt) {
      bf16x4 pk;
#pragma unroll
      for (int r = 0; r < 4; ++r) pk[r] = (bf16)p[rt * 4 + r];
      *(bf16x4*)(pws + tb(lrow, rt * 16 + lg * 4)) = pk;
    }
  };

#pragma unroll 1
  for (int st = 0; st <= qt1; ++st) {
    const char* Kst = Ktb + (size_t)st * 8192;
    const char* Vst = Vtb + (size_t)st * 4096;
    const bool hasA = (st <= qt0);

    // K fragments once, shared by both Q-states
    bf16x8 kf[4][2];
#pragma unroll
    for (int rt = 0; rt < 4; ++rt) {
      kf[rt][0] = *(const bf16x8*)(Kst + tb(rt * 16 + lrow, lg * 8));
      kf[rt][1] = *(const bf16x8*)(Kst + tb(rt * 16 + lrow, 32 + lg * 8));
    }

    f32x4 sB[4], sA[4];
    __builtin_amdgcn_s_setprio(1);
#pragma unroll
    for (int rt = 0; rt < 4; ++rt) {
      f32x4 a = {0.f, 0.f, 0.f, 0.f};
      a = __builtin_amdgcn_mfma_f32_16x16x32_bf16(kf[rt][0], qB0, a, 0, 0, 0);
      a = __builtin_amdgcn_mfma_f32_16x16x32_bf16(kf[rt][1], qB1, a, 0, 0, 0);
      sB[rt] = a;
    }
    if (hasA) {
#pragma unroll
      for (int rt = 0; rt < 4; ++rt) {
        f32x4 a = {0.f, 0.f, 0.f, 0.f};
        a = __builtin_amdgcn_mfma_f32_16x16x32_bf16(kf[rt][0], qA0, a, 0, 0, 0);
        a = __builtin_amdgcn_mfma_f32_16x16x32_bf16(kf[rt][1], qA1, a, 0, 0, 0);
        sA[rt] = a;
      }
    }
    __builtin_amdgcn_s_setprio(0);

    smfin(sB, l1, pwB, st == qt1);
    if (hasA) smfin(sA, l0, pwA, st == qt0);

    // V fragments once, shared by both states
    bf16x8 vf[2][2];
#pragma unroll
    for (int ks = 0; ks < 2; ++ks) {
      vf[ks][0] = *(const bf16x8*)(Vst + tb(lrow, ks * 32 + lg * 8));
      vf[ks][1] = *(const bf16x8*)(Vst + tb(16 + lrow, ks * 32 + lg * 8));
    }
    __builtin_amdgcn_s_setprio(1);
#pragma unroll
    for (int ks = 0; ks < 2; ++ks) {
      bf16x8 pfB = *(const bf16x8*)(pwB + tb(lrow, ks * 32 + lg * 8));
      o1a = __builtin_amdgcn_mfma_f32_16x16x32_bf16(vf[ks][0], pfB, o1a, 0, 0, 0);
      o1b = __builtin_amdgcn_mfma_f32_16x16x32_bf16(vf[ks][1], pfB, o1b, 0, 0, 0);
    }
    if (hasA) {
#pragma unroll
      for (int ks = 0; ks < 2; ++ks) {
        bf16x8 pfA = *(const bf16x8*)(pwA + tb(lrow, ks * 32 + lg * 8));
        o0a = __builtin_amdgcn_mfma_f32_16x16x32_bf16(vf[ks][0], pfA, o0a, 0, 0, 0);
        o0b = __builtin_amdgcn_mfma_f32_16x16x32_bf16(vf[ks][1], pfA, o0b, 0, 0, 0);
      }
    }
    __builtin_amdgcn_s_setprio(0);
  }

  // epilogue -> attTt swizzled tiles [n][ntt][kk][128x64]; rows=t, cols=h*32+dv
  auto epi = [&](int tg, float l, f32x4 oa, f32x4 ob) {
    const float inv = 1.0f / l;
    const int ntt = tg >> 7, row = tg & 127;
#pragma unroll
    for (int dt = 0; dt < 2; ++dt) {
      const f32x4 v = dt ? ob : oa;
      const int c = h * 32 + dt * 16 + lg * 4;
      char* tile = attTt + (((size_t)(n * 8 + ntt)) * 4 + (c >> 6)) * 16384;
      bf16x4 pk;
#pragma unroll
      for (int r = 0; r < 4; ++r) pk[r] = (bf16)(v[r] * inv);
      *(bf16x4*)(tile + tb(row, c & 63)) = pk;
    }
  };
  epi(tg0, l0, o0a, o0b);
  epi(tg1, l1, o1a, o1b);
}

// ---------------- kernel 3: output projection (ZERO-STAGING, 32t x 64o) ----------------
// Wot (128 KB) and attTt (4 MB, just written) are L2-hot: fragments direct
// from global, no LDS, no barriers. 1024 blocks = 4/CU.
__global__ __launch_bounds__(256) void k_proj(const char* __restrict__ attTt,
    const char* __restrict__ Wot, const float* __restrict__ bo, float* __restrict__ out) {
  const int tid = threadIdx.x;
  const int tm = blockIdx.x, om = blockIdx.y, n = blockIdx.z;
  const int w = tid >> 6, lane = tid & 63, lrow = lane & 15, lg = lane >> 4;
  const int wm = (w >> 1) * 16, wn = (w & 1) * 32;
  // A row t = tm*32 + wm + lrow -> tile ntt = tm>>2, row-in-tile (tm&3)*32+wm+lrow
  const char* gA = attTt + ((size_t)(n * 8 + (tm >> 2))) * 65536;
  const int arow = (tm & 3) * 32 + wm + lrow;
  // B row o = om*64 + wn + ni*16 + lrow -> tile mt = om>>1, row-in-tile (om&1)*64+...
  const char* gB = Wot + (size_t)(om >> 1) * 65536;
  const int brow = (om & 1) * 64 + wn + lrow;

  f32x4 acc[2] = {};
#pragma unroll
  for (int kk = 0; kk < 4; ++kk) {
    const char* At = gA + kk * 16384;
    const char* Bt = gB + kk * 16384;
    bf16x8 af[2], bv[2][2];
#pragma unroll
    for (int kh = 0; kh < 2; ++kh)
      af[kh] = *(const bf16x8*)(At + tb(arow, kh * 32 + lg * 8));
#pragma unroll
    for (int ni = 0; ni < 2; ++ni)
#pragma unroll
      for (int kh = 0; kh < 2; ++kh)
        bv[ni][kh] = *(const bf16x8*)(Bt + tb(brow + ni * 16, kh * 32 + lg * 8));
#pragma unroll
    for (int kh = 0; kh < 2; ++kh)
#pragma unroll
      for (int ni = 0; ni < 2; ++ni)
        acc[ni] = __builtin_amdgcn_mfma_f32_16x16x32_bf16(af[kh], bv[ni][kh], acc[ni], 0, 0, 0);
  }

  // epilogue: t = tm*32 + wm + lg*4 + r ; o = om*64 + wn + ni*16 + lrow
  const int t0 = tm * 32 + wm + lg * 4;
#pragma unroll
  for (int ni = 0; ni < 2; ++ni) {
    const int o = om * 64 + wn + ni * 16 + lrow;
    const float bb = bo[o];
    f32x4 v = acc[ni];
    v[0] += bb; v[1] += bb; v[2] += bb; v[3] += bb;
    *(f32x4*)(out + ((size_t)(n * C_DIM + o)) * T_DIM + t0) = v;
  }
}

extern "C" void kernel_launch(void* const* d_in, const int* in_sizes, int n_in,
                              void* d_out, int out_size, void* d_ws, size_t ws_size,
                              hipStream_t stream) {
  const float* x   = (const float*)d_in[0];
  const float* Wq  = (const float*)d_in[1];
  const float* bq  = (const float*)d_in[2];
  const float* Wkv = (const float*)d_in[3];
  const float* bkv = (const float*)d_in[4];
  const float* Wo  = (const float*)d_in[5];
  const float* bo  = (const float*)d_in[6];
  float* out = (float*)d_out;

  char* ws = (char*)d_ws;
  char* xTt   = ws;                      // 4 MB   [8][8][4][16KB]
  char* Wbt   = ws + (4u  << 20);        // 640 KB [10][4][16KB]
  char* Wot   = ws + (5u  << 20);        // 128 KB [2][4][16KB]
  bf16* q_ws  = (bf16*)(ws + (6u << 20)); // 8 MB  [64][1024][64]
  char* Kt    = ws + (14u << 20);        // 8 MB   [64][16][8KB]
  char* Vt    = ws + (22u << 20);        // 4 MB   [64][16][4KB]
  char* attTt = ws + (26u << 20);        // 4 MB   [8][8][4][16KB]

  k_prep<<<536, 256, 0, stream>>>(x, Wq, Wkv, Wo, xTt, Wbt, Wot);
  k_qkv<<<dim3(8, 10, 8), 256, 0, stream>>>(Wbt, xTt, bq, bkv, q_ws, Kt, Vt);
  k_attn<<<dim3(64, 8), 256, 0, stream>>>(q_ws, Kt, Vt, attTt);
  k_proj<<<dim3(32, 4, 8), 256, 0, stream>>>(attTt, Wot, bo, out);
}

// Round 14
// 50.082 us; speedup vs baseline: 1.1005x; 1.1005x over previous
//
#include <hip/hip_runtime.h>
#include <hip/hip_bf16.h>
#include <math.h>

typedef __bf16 bf16;
typedef __attribute__((ext_vector_type(4))) __bf16 bf16x4;
typedef __attribute__((ext_vector_type(8))) __bf16 bf16x8;
typedef __attribute__((ext_vector_type(4))) float f32x4;

#define T_DIM 1024
#define C_DIM 256
#define HEADS 8

// Pre-swizzled tile images: rows of 64 bf16 (128B), XOR-swizzled on 16B
// granules so ds_read_b128 column-slices are conflict-free (G4).
static __device__ __forceinline__ int tb(int row, int col) {
  return row * 128 + ((((col >> 3) ^ row) & 7) << 4) + ((col & 7) << 1);
}

// ---------------- kernel 0: prep ----------------
__global__ __launch_bounds__(256) void k_prep(const float* __restrict__ x,
    const float* __restrict__ Wq, const float* __restrict__ Wkv, const float* __restrict__ Wo,
    char* __restrict__ xTt, char* __restrict__ Wbt, char* __restrict__ Wot) {
  const int tid = threadIdx.x;
  const int b = blockIdx.x;
  if (b < 512) {
    __shared__ float tile[64][65];
    const int n = b >> 6, rem = b & 63, tt64 = rem >> 2, ct = (rem & 3) << 6;
    const float* xp = x + ((size_t)n * C_DIM + ct) * T_DIM + tt64 * 64;
    const int t4 = (tid & 15) * 4, c0 = tid >> 4;
#pragma unroll
    for (int i = 0; i < 4; ++i) {
      const int c = c0 + i * 16;
      float4 v = *(const float4*)(xp + (size_t)c * T_DIM + t4);
      tile[c][t4] = v.x; tile[c][t4 + 1] = v.y; tile[c][t4 + 2] = v.z; tile[c][t4 + 3] = v.w;
    }
    __syncthreads();
    char* dst = xTt + (((size_t)(n * 8 + (tt64 >> 1))) * 4 + (rem & 3)) * 16384;
    const int rbase = (tt64 & 1) * 64;
#pragma unroll
    for (int i = 0; i < 2; ++i) {
      const int idx = tid + i * 256;
      const int tl = idx >> 3, c8 = (idx & 7) * 8;
      bf16x8 v;
#pragma unroll
      for (int j = 0; j < 8; ++j) v[j] = (bf16)tile[c8 + j][tl];
      *(bf16x8*)(dst + tb(rbase + tl, c8)) = v;
    }
  } else {
    const bool isWo = (b >= 532);
    const int o0 = (b - (isWo ? 532 : 512)) * 64;
#pragma unroll
    for (int i = 0; i < 8; ++i) {
      const int idx = tid + i * 256;
      const int row = idx >> 5, c8 = (idx & 31) * 8;
      const int o = o0 + row;
      const float* src = isWo ? (Wo + (size_t)o * C_DIM + c8)
                              : (o < 512 ? Wq + (size_t)o * C_DIM + c8
                                         : Wkv + (size_t)(o - 512) * C_DIM + c8);
      float4 a = *(const float4*)src;
      float4 bq4 = *(const float4*)(src + 4);
      bf16x8 v;
      v[0]=(bf16)a.x; v[1]=(bf16)a.y; v[2]=(bf16)a.z; v[3]=(bf16)a.w;
      v[4]=(bf16)bq4.x; v[5]=(bf16)bq4.y; v[6]=(bf16)bq4.z; v[7]=(bf16)bq4.w;
      char* base = isWo ? Wot : Wbt;
      char* dst = base + (((size_t)(o >> 7)) * 4 + (c8 >> 6)) * 16384;
      *(bf16x8*)(dst + tb(o & 127, c8 & 63)) = v;
    }
  }
}

// ---------------- kernel 1: QKV projection (128x128, BK=64, T14 reg-staged) ----------------
// Per iter: bar -> ds_write(regs) -> issue next loads -> bar -> MFMA.
__global__ __launch_bounds__(256) void k_qkv(const char* __restrict__ Wbt, const char* __restrict__ xTt,
    const float* __restrict__ bq, const float* __restrict__ bkv,
    bf16* __restrict__ q_ws, char* __restrict__ Kt, char* __restrict__ Vt) {
  __shared__ __attribute__((aligned(128))) unsigned char smem[34816];
  const int tid = threadIdx.x;
  const int nt = blockIdx.x, mt = blockIdx.y, n = blockIdx.z;
  const int w = tid >> 6, lane = tid & 63, lrow = lane & 15, lg = lane >> 4;
  const int wm = (w >> 1) * 64, wn = (w & 1) * 64;
  const char* gA = Wbt + (size_t)mt * 65536;
  const char* gB = xTt + ((size_t)(n * 8 + nt)) * 65536;
  const float s2 = 0.18033688f;   // 0.125 * log2(e)
  const int coff = w * 1024 + lane * 16;

  bf16x8 sA0, sA1, sA2, sA3, sB0, sB1, sB2, sB3;
  auto issue = [&](int kk) {
    const char* a = gA + kk * 16384 + coff;
    sA0 = *(const bf16x8*)(a);         sA1 = *(const bf16x8*)(a + 4096);
    sA2 = *(const bf16x8*)(a + 8192);  sA3 = *(const bf16x8*)(a + 12288);
    const char* bsrc = gB + kk * 16384 + coff;
    sB0 = *(const bf16x8*)(bsrc);        sB1 = *(const bf16x8*)(bsrc + 4096);
    sB2 = *(const bf16x8*)(bsrc + 8192); sB3 = *(const bf16x8*)(bsrc + 12288);
  };

  f32x4 acc[4][4] = {};
  issue(0);
#pragma unroll 1
  for (int kk = 0; kk < 4; ++kk) {
    __syncthreads();                       // prev iter LDS reads done (WAR)
    char* da = (char*)smem + coff;
    *(bf16x8*)(da)         = sA0; *(bf16x8*)(da + 4096)  = sA1;
    *(bf16x8*)(da + 8192)  = sA2; *(bf16x8*)(da + 12288) = sA3;
    char* db = (char*)smem + 16384 + coff;
    *(bf16x8*)(db)         = sB0; *(bf16x8*)(db + 4096)  = sB1;
    *(bf16x8*)(db + 8192)  = sB2; *(bf16x8*)(db + 12288) = sB3;
    if (kk < 3) issue(kk + 1);             // latency hides under this iter's MFMA
    __syncthreads();                       // writes visible
    const char* As = (const char*)smem;
    const char* Bs = As + 16384;
    bf16x8 af[4][2], bv[4][2];
#pragma unroll
    for (int mi = 0; mi < 4; ++mi)
#pragma unroll
      for (int kh = 0; kh < 2; ++kh)
        af[mi][kh] = *(const bf16x8*)(As + tb(wm + mi * 16 + lrow, kh * 32 + lg * 8));
#pragma unroll
    for (int ni = 0; ni < 4; ++ni)
#pragma unroll
      for (int kh = 0; kh < 2; ++kh)
        bv[ni][kh] = *(const bf16x8*)(Bs + tb(wn + ni * 16 + lrow, kh * 32 + lg * 8));
#pragma unroll
    for (int kh = 0; kh < 2; ++kh)
#pragma unroll
      for (int mi = 0; mi < 4; ++mi)
#pragma unroll
        for (int ni = 0; ni < 4; ++ni)
          acc[mi][ni] = __builtin_amdgcn_mfma_f32_16x16x32_bf16(af[mi][kh], bv[ni][kh], acc[mi][ni], 0, 0, 0);
  }
  __syncthreads();                         // compute done before epilogue LDS reuse

  const int obase = mt * 128 + wm + lg * 4;
  const int tcol0 = nt * 128 + wn + lrow;
  if (mt < 8) {
#pragma unroll
    for (int mi = 0; mi < 4; ++mi) {
      const int o = obase + mi * 16;
      if (mt < 4) {                      // Q (pre-scaled by s2) -> q_ws[nh][t][64]
        const float4 bb = *(const float4*)(bq + o);
        const int nh = n * 8 + (o >> 6), d = o & 63;
        bf16* qrow = q_ws + (size_t)nh * (T_DIM * 64) + d;
#pragma unroll
        for (int ni = 0; ni < 4; ++ni) {
          const int t = tcol0 + ni * 16;
          f32x4 v = acc[mi][ni];
          bf16x4 pk;
          pk[0]=(bf16)((v[0]+bb.x)*s2); pk[1]=(bf16)((v[1]+bb.y)*s2);
          pk[2]=(bf16)((v[2]+bb.z)*s2); pk[3]=(bf16)((v[3]+bb.w)*s2);
          *(bf16x4*)(qrow + (size_t)t * 64) = pk;
        }
      } else {                           // K -> Kt swizzled tiles [nh][st][64x64]
        const int o2 = o - 512;
        const float4 bb = *(const float4*)(bkv + o2);
        const int nh = n * 8 + (o2 >> 6), d = o2 & 63;
        char* tbase = Kt + (size_t)nh * 16 * 8192;
#pragma unroll
        for (int ni = 0; ni < 4; ++ni) {
          const int t = tcol0 + ni * 16;
          f32x4 v = acc[mi][ni];
          bf16x4 pk;
          pk[0]=(bf16)(v[0]+bb.x); pk[1]=(bf16)(v[1]+bb.y); pk[2]=(bf16)(v[2]+bb.z); pk[3]=(bf16)(v[3]+bb.w);
          *(bf16x4*)(tbase + (t >> 6) * 8192 + tb(t & 63, d)) = pk;
        }
      }
    }
  } else {
    // V route: acc -> LDS [128][132] (+bias), then 16B granule stores into Vt.
    bf16* tp = (bf16*)smem;
#pragma unroll
    for (int mi = 0; mi < 4; ++mi) {
      const int o3g = (mt - 8) * 128 + wm + mi * 16 + lg * 4;
      const float4 bb = *(const float4*)(bkv + 512 + o3g);
      const float* bbp = (const float*)&bb;
      const int o3l = wm + mi * 16 + lg * 4;
#pragma unroll
      for (int ni = 0; ni < 4; ++ni) {
        const int tl = wn + ni * 16 + lrow;
        f32x4 v = acc[mi][ni];
#pragma unroll
        for (int r = 0; r < 4; ++r)
          tp[(o3l + r) * 132 + tl] = (bf16)(v[r] + bbp[r]);
      }
    }
    __syncthreads();
    const int row = tid >> 1, half = tid & 1;
    const int o3 = (mt - 8) * 128 + row;
    const int nh = n * 8 + (o3 >> 5), dv = o3 & 31;
    char* tile = Vt + (size_t)nh * 16 * 4096 + (nt * 2 + half) * 4096;
    const bf16* src = tp + row * 132 + half * 64;
#pragma unroll
    for (int g = 0; g < 8; ++g) {
      bf16x4 lo = *(const bf16x4*)(src + g * 8);
      bf16x4 hi = *(const bf16x4*)(src + g * 8 + 4);
      bf16x8 vv;
      vv[0]=lo[0]; vv[1]=lo[1]; vv[2]=lo[2]; vv[3]=lo[3];
      vv[4]=hi[0]; vv[5]=hi[1]; vv[6]=hi[2]; vv[7]=hi[3];
      *(bf16x8*)(tile + tb(dv, g * 8)) = vv;
    }
  }
}

// ---------------- kernel 2: causal attention (static-max, T14 reg-staged) ----------------
// LDS: K0 0 | K1 8K | V0 16K | V1 20K | P 24K + w*2K (per-wave, reused across
// subs -- same-wave LDS ordering). Per iter: bar -> ds_write -> issue next -> bar -> compute.
__global__ __launch_bounds__(256) void k_attn(const bf16* __restrict__ q_ws,
    const char* __restrict__ Kt, const char* __restrict__ Vt, char* __restrict__ attTt) {
  __shared__ __attribute__((aligned(128))) unsigned char smem[32768];
  const int tid = threadIdx.x;
  const int nh = blockIdx.x, qp = blockIdx.y;
  const int w = tid >> 6, lane = tid & 63, lrow = lane & 15, lg = lane >> 4;
  const int tl = w * 16 + lrow;
  const char* Ktb = Kt + (size_t)nh * 16 * 8192;
  const char* Vtb = Vt + (size_t)nh * 16 * 4096;
  const int n = nh >> 3, h = nh & 7;
  const int koff = w * 1024 + lane * 16;       // K: 2 chunks of 4K
  const int voff = (tid >> 6) * 1024 + (tid & 63) * 16;  // V: 1 chunk of 4K

  const int qt0 = qp, qt1 = 15 - qp;
  const int tg0 = qt0 * 64 + tl, tg1 = qt1 * 64 + tl;
  const bf16* qb0 = q_ws + ((size_t)nh * T_DIM + tg0) * 64;
  const bf16* qb1 = q_ws + ((size_t)nh * T_DIM + tg1) * 64;
  const bf16x8 qA0 = *(const bf16x8*)(qb0 + lg * 8);
  const bf16x8 qA1 = *(const bf16x8*)(qb0 + 32 + lg * 8);
  const bf16x8 qB0 = *(const bf16x8*)(qb1 + lg * 8);
  const bf16x8 qB1 = *(const bf16x8*)(qb1 + 32 + lg * 8);

  float l0 = 0.f, l1 = 0.f;
  f32x4 o0a = {}, o0b = {}, o1a = {}, o1b = {};

  bf16x8 s0, s1, s2, s3, s4, s5;     // staged K0(2),K1(2),V0,V1
  auto issue = [&](int st2, bool has1) {
    const char* k0 = Ktb + (size_t)st2 * 8192 + koff;
    s0 = *(const bf16x8*)(k0);
    s1 = *(const bf16x8*)(k0 + 4096);
    s4 = *(const bf16x8*)(Vtb + (size_t)st2 * 4096 + voff);
    if (has1) {
      const char* k1 = k0 + 8192;
      s2 = *(const bf16x8*)(k1);
      s3 = *(const bf16x8*)(k1 + 4096);
      s5 = *(const bf16x8*)(Vtb + (size_t)(st2 + 1) * 4096 + voff);
    }
  };

  auto proc = [&](bf16x8 qf0, bf16x8 qf1, float& l, f32x4& oa, f32x4& ob,
                  const char* Kbs, const char* Vbs, char* pws, bool diag) {
    f32x4 sacc[4];
    __builtin_amdgcn_s_setprio(1);
#pragma unroll
    for (int rt = 0; rt < 4; ++rt) {
      f32x4 a = {0.f, 0.f, 0.f, 0.f};
      bf16x8 kf0 = *(const bf16x8*)(Kbs + tb(rt * 16 + lrow, lg * 8));
      a = __builtin_amdgcn_mfma_f32_16x16x32_bf16(kf0, qf0, a, 0, 0, 0);
      bf16x8 kf1 = *(const bf16x8*)(Kbs + tb(rt * 16 + lrow, 32 + lg * 8));
      a = __builtin_amdgcn_mfma_f32_16x16x32_bf16(kf1, qf1, a, 0, 0, 0);
      sacc[rt] = a;
    }
    __builtin_amdgcn_s_setprio(0);
    float p[16];
#pragma unroll
    for (int rt = 0; rt < 4; ++rt)
#pragma unroll
      for (int r = 0; r < 4; ++r) {
        float e = __builtin_amdgcn_exp2f(sacc[rt][r]);
        if (diag && (rt * 16 + lg * 4 + r) > tl) e = 0.f;
        p[rt * 4 + r] = e;
      }
    float t0 = (p[0] + p[1]) + (p[2] + p[3]);
    float t1 = (p[4] + p[5]) + (p[6] + p[7]);
    float t2 = (p[8] + p[9]) + (p[10] + p[11]);
    float t3 = (p[12] + p[13]) + (p[14] + p[15]);
    float ps = (t0 + t1) + (t2 + t3);
    ps += __shfl_xor(ps, 16);
    ps += __shfl_xor(ps, 32);
    l += ps;
#pragma unroll
    for (int rt = 0; rt < 4; ++rt) {
      bf16x4 pk;
#pragma unroll
      for (int r = 0; r < 4; ++r) pk[r] = (bf16)p[rt * 4 + r];
      *(bf16x4*)(pws + tb(lrow, rt * 16 + lg * 4)) = pk;
    }
    __builtin_amdgcn_s_setprio(1);
#pragma unroll
    for (int ks = 0; ks < 2; ++ks) {
      bf16x8 pf = *(const bf16x8*)(pws + tb(lrow, ks * 32 + lg * 8));
      bf16x8 vf0 = *(const bf16x8*)(Vbs + tb(lrow, ks * 32 + lg * 8));
      oa = __builtin_amdgcn_mfma_f32_16x16x32_bf16(vf0, pf, oa, 0, 0, 0);
      bf16x8 vf1 = *(const bf16x8*)(Vbs + tb(16 + lrow, ks * 32 + lg * 8));
      ob = __builtin_amdgcn_mfma_f32_16x16x32_bf16(vf1, pf, ob, 0, 0, 0);
    }
    __builtin_amdgcn_s_setprio(0);
  };

  issue(0, 1 <= qt1);
#pragma unroll 1
  for (int st2 = 0; st2 <= qt1; st2 += 2) {
    const bool has1 = (st2 + 1 <= qt1);
    __syncthreads();                     // prev iter LDS reads done (WAR)
    {
      char* kd = (char*)smem + koff;
      *(bf16x8*)(kd) = s0;
      *(bf16x8*)(kd + 4096) = s1;
      *(bf16x8*)((char*)smem + 16384 + voff) = s4;
      if (has1) {
        *(bf16x8*)(kd + 8192) = s2;
        *(bf16x8*)(kd + 12288) = s3;
        *(bf16x8*)((char*)smem + 20480 + voff) = s5;
      }
    }
    const int nst2 = st2 + 2;
    if (nst2 <= qt1) issue(nst2, nst2 + 1 <= qt1);  // hides under this iter's compute
    __syncthreads();                     // writes visible
    const int nsub = has1 ? 2 : 1;
#pragma unroll 1
    for (int sub = 0; sub < nsub; ++sub) {
      const int stk = st2 + sub;
      const char* Kbs = (const char*)smem + sub * 8192;
      const char* Vbs = (const char*)smem + 16384 + sub * 4096;
      char* pws = (char*)smem + 24576 + w * 2048;
      proc(qB0, qB1, l1, o1a, o1b, Kbs, Vbs, pws, stk == qt1);
      if (stk <= qt0)
        proc(qA0, qA1, l0, o0a, o0b, Kbs, Vbs, pws, stk == qt0);
    }
  }

  auto epi = [&](int tg, float l, f32x4 oa, f32x4 ob) {
    const float inv = 1.0f / l;
    const int ntt = tg >> 7, row = tg & 127;
#pragma unroll
    for (int dt = 0; dt < 2; ++dt) {
      const f32x4 v = dt ? ob : oa;
      const int c = h * 32 + dt * 16 + lg * 4;
      char* tile = attTt + (((size_t)(n * 8 + ntt)) * 4 + (c >> 6)) * 16384;
      bf16x4 pk;
#pragma unroll
      for (int r = 0; r < 4; ++r) pk[r] = (bf16)(v[r] * inv);
      *(bf16x4*)(tile + tb(row, c & 63)) = pk;
    }
  };
  epi(tg0, l0, o0a, o0b);
  epi(tg1, l1, o1a, o1b);
}

// ---------------- kernel 3: output projection (64x64, BK=64, T14 reg-staged) ----------------
__global__ __launch_bounds__(256) void k_proj(const char* __restrict__ attTt,
    const char* __restrict__ Wot, const float* __restrict__ bo, float* __restrict__ out) {
  __shared__ __attribute__((aligned(128))) unsigned char smem[16384]; // A 8K | B 8K
  const int tid = threadIdx.x;
  const int tm = blockIdx.x, om = blockIdx.y, n = blockIdx.z;
  const int w = tid >> 6, lane = tid & 63, lrow = lane & 15, lg = lane >> 4;
  const int wm = (w >> 1) * 32, wn = (w & 1) * 32;
  const char* gA = attTt + ((size_t)(n * 8 + (tm >> 1))) * 65536 + (tm & 1) * 8192;
  const char* gB = Wot + (size_t)(om >> 1) * 65536 + (om & 1) * 8192;
  const int coff = w * 1024 + lane * 16;

  bf16x8 pA0, pA1, pB0, pB1;
  auto issue = [&](int kk) {
    const char* a = gA + kk * 16384 + coff;
    pA0 = *(const bf16x8*)(a); pA1 = *(const bf16x8*)(a + 4096);
    const char* bsrc = gB + kk * 16384 + coff;
    pB0 = *(const bf16x8*)(bsrc); pB1 = *(const bf16x8*)(bsrc + 4096);
  };

  f32x4 acc[2][2] = {};
  issue(0);
#pragma unroll 1
  for (int kk = 0; kk < 4; ++kk) {
    __syncthreads();
    char* da = (char*)smem + coff;
    *(bf16x8*)(da) = pA0; *(bf16x8*)(da + 4096) = pA1;
    char* db = (char*)smem + 8192 + coff;
    *(bf16x8*)(db) = pB0; *(bf16x8*)(db + 4096) = pB1;
    if (kk < 3) issue(kk + 1);
    __syncthreads();
    const char* As = (const char*)smem;
    const char* Bs = As + 8192;
    bf16x8 af[2][2], bv[2][2];
#pragma unroll
    for (int mi = 0; mi < 2; ++mi)
#pragma unroll
      for (int kh = 0; kh < 2; ++kh)
        af[mi][kh] = *(const bf16x8*)(As + tb(wm + mi * 16 + lrow, kh * 32 + lg * 8));
#pragma unroll
    for (int ni = 0; ni < 2; ++ni)
#pragma unroll
      for (int kh = 0; kh < 2; ++kh)
        bv[ni][kh] = *(const bf16x8*)(Bs + tb(wn + ni * 16 + lrow, kh * 32 + lg * 8));
#pragma unroll
    for (int kh = 0; kh < 2; ++kh)
#pragma unroll
      for (int mi = 0; mi < 2; ++mi)
#pragma unroll
        for (int ni = 0; ni < 2; ++ni)
          acc[mi][ni] = __builtin_amdgcn_mfma_f32_16x16x32_bf16(af[mi][kh], bv[ni][kh], acc[mi][ni], 0, 0, 0);
  }

  const int t0b = tm * 64 + wm + lg * 4;
  const int ob = om * 64 + wn + lrow;
#pragma unroll
  for (int mi = 0; mi < 2; ++mi) {
    const int t0 = t0b + mi * 16;
#pragma unroll
    for (int ni = 0; ni < 2; ++ni) {
      const int o = ob + ni * 16;
      const float bb = bo[o];
      f32x4 v = acc[mi][ni];
      v[0] += bb; v[1] += bb; v[2] += bb; v[3] += bb;
      *(f32x4*)(out + ((size_t)(n * C_DIM + o)) * T_DIM + t0) = v;
    }
  }
}

extern "C" void kernel_launch(void* const* d_in, const int* in_sizes, int n_in,
                              void* d_out, int out_size, void* d_ws, size_t ws_size,
                              hipStream_t stream) {
  const float* x   = (const float*)d_in[0];
  const float* Wq  = (const float*)d_in[1];
  const float* bq  = (const float*)d_in[2];
  const float* Wkv = (const float*)d_in[3];
  const float* bkv = (const float*)d_in[4];
  const float* Wo  = (const float*)d_in[5];
  const float* bo  = (const float*)d_in[6];
  float* out = (float*)d_out;

  char* ws = (char*)d_ws;
  char* xTt   = ws;                      // 4 MB   [8][8][4][16KB]
  char* Wbt   = ws + (4u  << 20);        // 640 KB [10][4][16KB]
  char* Wot   = ws + (5u  << 20);        // 128 KB [2][4][16KB]
  bf16* q_ws  = (bf16*)(ws + (6u << 20)); // 8 MB  [64][1024][64]
  char* Kt    = ws + (14u << 20);        // 8 MB   [64][16][8KB]
  char* Vt    = ws + (22u << 20);        // 4 MB   [64][16][4KB]
  char* attTt = ws + (26u << 20);        // 4 MB   [8][8][4][16KB]

  k_prep<<<536, 256, 0, stream>>>(x, Wq, Wkv, Wo, xTt, Wbt, Wot);
  k_qkv<<<dim3(8, 10, 8), 256, 0, stream>>>(Wbt, xTt, bq, bkv, q_ws, Kt, Vt);
  k_attn<<<dim3(64, 8), 256, 0, stream>>>(q_ws, Kt, Vt, attTt);
  k_proj<<<dim3(16, 4, 8), 256, 0, stream>>>(attTt, Wot, bo, out);
}

// Round 15
// 49.991 us; speedup vs baseline: 1.1025x; 1.0018x over previous
//
#include <hip/hip_runtime.h>
#include <hip/hip_bf16.h>
#include <math.h>

typedef __bf16 bf16;
typedef __attribute__((ext_vector_type(4))) __bf16 bf16x4;
typedef __attribute__((ext_vector_type(8))) __bf16 bf16x8;
typedef __attribute__((ext_vector_type(4))) float f32x4;

#define T_DIM 1024
#define C_DIM 256
#define HEADS 8

// Pre-swizzled tile images: rows of 64 bf16 (128B), XOR-swizzled on 16B
// granules so ds_read_b128 column-slices are conflict-free (G4).
static __device__ __forceinline__ int tb(int row, int col) {
  return row * 128 + ((((col >> 3) ^ row) & 7) << 4) + ((col & 7) << 1);
}

// ---------------- kernel 0: prep ----------------
__global__ __launch_bounds__(256) void k_prep(const float* __restrict__ x,
    const float* __restrict__ Wq, const float* __restrict__ Wkv, const float* __restrict__ Wo,
    char* __restrict__ xTt, char* __restrict__ Wbt, char* __restrict__ Wot) {
  const int tid = threadIdx.x;
  const int b = blockIdx.x;
  if (b < 512) {
    __shared__ float tile[64][65];
    const int n = b >> 6, rem = b & 63, tt64 = rem >> 2, ct = (rem & 3) << 6;
    const float* xp = x + ((size_t)n * C_DIM + ct) * T_DIM + tt64 * 64;
    const int t4 = (tid & 15) * 4, c0 = tid >> 4;
#pragma unroll
    for (int i = 0; i < 4; ++i) {
      const int c = c0 + i * 16;
      float4 v = *(const float4*)(xp + (size_t)c * T_DIM + t4);
      tile[c][t4] = v.x; tile[c][t4 + 1] = v.y; tile[c][t4 + 2] = v.z; tile[c][t4 + 3] = v.w;
    }
    __syncthreads();
    char* dst = xTt + (((size_t)(n * 8 + (tt64 >> 1))) * 4 + (rem & 3)) * 16384;
    const int rbase = (tt64 & 1) * 64;
#pragma unroll
    for (int i = 0; i < 2; ++i) {
      const int idx = tid + i * 256;
      const int tl = idx >> 3, c8 = (idx & 7) * 8;
      bf16x8 v;
#pragma unroll
      for (int j = 0; j < 8; ++j) v[j] = (bf16)tile[c8 + j][tl];
      *(bf16x8*)(dst + tb(rbase + tl, c8)) = v;
    }
  } else {
    const bool isWo = (b >= 532);
    const int o0 = (b - (isWo ? 532 : 512)) * 64;
#pragma unroll
    for (int i = 0; i < 8; ++i) {
      const int idx = tid + i * 256;
      const int row = idx >> 5, c8 = (idx & 31) * 8;
      const int o = o0 + row;
      const float* src = isWo ? (Wo + (size_t)o * C_DIM + c8)
                              : (o < 512 ? Wq + (size_t)o * C_DIM + c8
                                         : Wkv + (size_t)(o - 512) * C_DIM + c8);
      float4 a = *(const float4*)src;
      float4 bq4 = *(const float4*)(src + 4);
      bf16x8 v;
      v[0]=(bf16)a.x; v[1]=(bf16)a.y; v[2]=(bf16)a.z; v[3]=(bf16)a.w;
      v[4]=(bf16)bq4.x; v[5]=(bf16)bq4.y; v[6]=(bf16)bq4.z; v[7]=(bf16)bq4.w;
      char* base = isWo ? Wot : Wbt;
      char* dst = base + (((size_t)(o >> 7)) * 4 + (c8 >> 6)) * 16384;
      *(bf16x8*)(dst + tb(o & 127, c8 & 63)) = v;
    }
  }
}

// ---------------- kernel 1: QKV projection (128x128, BK=64, T14 reg-staged) ----------------
// Per iter: bar -> ds_write(regs) -> issue next loads -> bar -> MFMA.
__global__ __launch_bounds__(256) void k_qkv(const char* __restrict__ Wbt, const char* __restrict__ xTt,
    const float* __restrict__ bq, const float* __restrict__ bkv,
    bf16* __restrict__ q_ws, char* __restrict__ Kt, char* __restrict__ Vt) {
  __shared__ __attribute__((aligned(128))) unsigned char smem[34816];
  const int tid = threadIdx.x;
  const int nt = blockIdx.x, mt = blockIdx.y, n = blockIdx.z;
  const int w = tid >> 6, lane = tid & 63, lrow = lane & 15, lg = lane >> 4;
  const int wm = (w >> 1) * 64, wn = (w & 1) * 64;
  const char* gA = Wbt + (size_t)mt * 65536;
  const char* gB = xTt + ((size_t)(n * 8 + nt)) * 65536;
  const float s2 = 0.18033688f;   // 0.125 * log2(e)
  const int coff = w * 1024 + lane * 16;

  bf16x8 sA0, sA1, sA2, sA3, sB0, sB1, sB2, sB3;
  auto issue = [&](int kk) {
    const char* a = gA + kk * 16384 + coff;
    sA0 = *(const bf16x8*)(a);         sA1 = *(const bf16x8*)(a + 4096);
    sA2 = *(const bf16x8*)(a + 8192);  sA3 = *(const bf16x8*)(a + 12288);
    const char* bsrc = gB + kk * 16384 + coff;
    sB0 = *(const bf16x8*)(bsrc);        sB1 = *(const bf16x8*)(bsrc + 4096);
    sB2 = *(const bf16x8*)(bsrc + 8192); sB3 = *(const bf16x8*)(bsrc + 12288);
  };

  f32x4 acc[4][4] = {};
  issue(0);
#pragma unroll 1
  for (int kk = 0; kk < 4; ++kk) {
    __syncthreads();                       // prev iter LDS reads done (WAR)
    char* da = (char*)smem + coff;
    *(bf16x8*)(da)         = sA0; *(bf16x8*)(da + 4096)  = sA1;
    *(bf16x8*)(da + 8192)  = sA2; *(bf16x8*)(da + 12288) = sA3;
    char* db = (char*)smem + 16384 + coff;
    *(bf16x8*)(db)         = sB0; *(bf16x8*)(db + 4096)  = sB1;
    *(bf16x8*)(db + 8192)  = sB2; *(bf16x8*)(db + 12288) = sB3;
    if (kk < 3) issue(kk + 1);             // latency hides under this iter's MFMA
    __syncthreads();                       // writes visible
    const char* As = (const char*)smem;
    const char* Bs = As + 16384;
    bf16x8 af[4][2], bv[4][2];
#pragma unroll
    for (int mi = 0; mi < 4; ++mi)
#pragma unroll
      for (int kh = 0; kh < 2; ++kh)
        af[mi][kh] = *(const bf16x8*)(As + tb(wm + mi * 16 + lrow, kh * 32 + lg * 8));
#pragma unroll
    for (int ni = 0; ni < 4; ++ni)
#pragma unroll
      for (int kh = 0; kh < 2; ++kh)
        bv[ni][kh] = *(const bf16x8*)(Bs + tb(wn + ni * 16 + lrow, kh * 32 + lg * 8));
#pragma unroll
    for (int kh = 0; kh < 2; ++kh)
#pragma unroll
      for (int mi = 0; mi < 4; ++mi)
#pragma unroll
        for (int ni = 0; ni < 4; ++ni)
          acc[mi][ni] = __builtin_amdgcn_mfma_f32_16x16x32_bf16(af[mi][kh], bv[ni][kh], acc[mi][ni], 0, 0, 0);
  }
  __syncthreads();                         // compute done before epilogue LDS reuse

  const int obase = mt * 128 + wm + lg * 4;
  const int tcol0 = nt * 128 + wn + lrow;
  if (mt < 8) {
#pragma unroll
    for (int mi = 0; mi < 4; ++mi) {
      const int o = obase + mi * 16;
      if (mt < 4) {                      // Q (pre-scaled by s2) -> q_ws[nh][t][64]
        const float4 bb = *(const float4*)(bq + o);
        const int nh = n * 8 + (o >> 6), d = o & 63;
        bf16* qrow = q_ws + (size_t)nh * (T_DIM * 64) + d;
#pragma unroll
        for (int ni = 0; ni < 4; ++ni) {
          const int t = tcol0 + ni * 16;
          f32x4 v = acc[mi][ni];
          bf16x4 pk;
          pk[0]=(bf16)((v[0]+bb.x)*s2); pk[1]=(bf16)((v[1]+bb.y)*s2);
          pk[2]=(bf16)((v[2]+bb.z)*s2); pk[3]=(bf16)((v[3]+bb.w)*s2);
          *(bf16x4*)(qrow + (size_t)t * 64) = pk;
        }
      } else {                           // K -> Kt swizzled tiles [nh][st][64x64]
        const int o2 = o - 512;
        const float4 bb = *(const float4*)(bkv + o2);
        const int nh = n * 8 + (o2 >> 6), d = o2 & 63;
        char* tbase = Kt + (size_t)nh * 16 * 8192;
#pragma unroll
        for (int ni = 0; ni < 4; ++ni) {
          const int t = tcol0 + ni * 16;
          f32x4 v = acc[mi][ni];
          bf16x4 pk;
          pk[0]=(bf16)(v[0]+bb.x); pk[1]=(bf16)(v[1]+bb.y); pk[2]=(bf16)(v[2]+bb.z); pk[3]=(bf16)(v[3]+bb.w);
          *(bf16x4*)(tbase + (t >> 6) * 8192 + tb(t & 63, d)) = pk;
        }
      }
    }
  } else {
    // V route: acc -> LDS [128][132] (+bias), then 16B granule stores into Vt.
    bf16* tp = (bf16*)smem;
#pragma unroll
    for (int mi = 0; mi < 4; ++mi) {
      const int o3g = (mt - 8) * 128 + wm + mi * 16 + lg * 4;
      const float4 bb = *(const float4*)(bkv + 512 + o3g);
      const float* bbp = (const float*)&bb;
      const int o3l = wm + mi * 16 + lg * 4;
#pragma unroll
      for (int ni = 0; ni < 4; ++ni) {
        const int tl = wn + ni * 16 + lrow;
        f32x4 v = acc[mi][ni];
#pragma unroll
        for (int r = 0; r < 4; ++r)
          tp[(o3l + r) * 132 + tl] = (bf16)(v[r] + bbp[r]);
      }
    }
    __syncthreads();
    const int row = tid >> 1, half = tid & 1;
    const int o3 = (mt - 8) * 128 + row;
    const int nh = n * 8 + (o3 >> 5), dv = o3 & 31;
    char* tile = Vt + (size_t)nh * 16 * 4096 + (nt * 2 + half) * 4096;
    const bf16* src = tp + row * 132 + half * 64;
#pragma unroll
    for (int g = 0; g < 8; ++g) {
      bf16x4 lo = *(const bf16x4*)(src + g * 8);
      bf16x4 hi = *(const bf16x4*)(src + g * 8 + 4);
      bf16x8 vv;
      vv[0]=lo[0]; vv[1]=lo[1]; vv[2]=lo[2]; vv[3]=lo[3];
      vv[4]=hi[0]; vv[5]=hi[1]; vv[6]=hi[2]; vv[7]=hi[3];
      *(bf16x8*)(tile + tb(dv, g * 8)) = vv;
    }
  }
}

// ---------------- kernel 2: causal attention (static-max, T14, deferred l-reduce) ----------------
// l stays LANE-LOCAL partial through the sweep (removes 2 shfl + dependency per
// proc, x17 procs); the 4-lane-group xor-reduce happens once in the epilogue.
// LDS: K0 0 | K1 8K | V0 16K | V1 20K | P 24K + w*2K. Proven R10 topology.
__global__ __launch_bounds__(256) void k_attn(const bf16* __restrict__ q_ws,
    const char* __restrict__ Kt, const char* __restrict__ Vt, char* __restrict__ attTt) {
  __shared__ __attribute__((aligned(128))) unsigned char smem[32768];
  const int tid = threadIdx.x;
  const int nh = blockIdx.x, qp = blockIdx.y;
  const int w = tid >> 6, lane = tid & 63, lrow = lane & 15, lg = lane >> 4;
  const int tl = w * 16 + lrow;
  const char* Ktb = Kt + (size_t)nh * 16 * 8192;
  const char* Vtb = Vt + (size_t)nh * 16 * 4096;
  const int n = nh >> 3, h = nh & 7;
  const int koff = w * 1024 + lane * 16;       // K: 2 chunks of 4K
  const int voff = (tid >> 6) * 1024 + (tid & 63) * 16;  // V: 1 chunk of 4K

  const int qt0 = qp, qt1 = 15 - qp;
  const int tg0 = qt0 * 64 + tl, tg1 = qt1 * 64 + tl;
  const bf16* qb0 = q_ws + ((size_t)nh * T_DIM + tg0) * 64;
  const bf16* qb1 = q_ws + ((size_t)nh * T_DIM + tg1) * 64;
  const bf16x8 qA0 = *(const bf16x8*)(qb0 + lg * 8);
  const bf16x8 qA1 = *(const bf16x8*)(qb0 + 32 + lg * 8);
  const bf16x8 qB0 = *(const bf16x8*)(qb1 + lg * 8);
  const bf16x8 qB1 = *(const bf16x8*)(qb1 + 32 + lg * 8);

  float l0 = 0.f, l1 = 0.f;                  // lane-local partials
  f32x4 o0a = {}, o0b = {}, o1a = {}, o1b = {};

  bf16x8 s0, s1, s2, s3, s4, s5;     // staged K0(2),K1(2),V0,V1
  auto issue = [&](int st2, bool has1) {
    const char* k0 = Ktb + (size_t)st2 * 8192 + koff;
    s0 = *(const bf16x8*)(k0);
    s1 = *(const bf16x8*)(k0 + 4096);
    s4 = *(const bf16x8*)(Vtb + (size_t)st2 * 4096 + voff);
    if (has1) {
      const char* k1 = k0 + 8192;
      s2 = *(const bf16x8*)(k1);
      s3 = *(const bf16x8*)(k1 + 4096);
      s5 = *(const bf16x8*)(Vtb + (size_t)(st2 + 1) * 4096 + voff);
    }
  };

  auto proc = [&](bf16x8 qf0, bf16x8 qf1, float& l, f32x4& oa, f32x4& ob,
                  const char* Kbs, const char* Vbs, char* pws, bool diag) {
    f32x4 sacc[4];
    __builtin_amdgcn_s_setprio(1);
#pragma unroll
    for (int rt = 0; rt < 4; ++rt) {
      f32x4 a = {0.f, 0.f, 0.f, 0.f};
      bf16x8 kf0 = *(const bf16x8*)(Kbs + tb(rt * 16 + lrow, lg * 8));
      a = __builtin_amdgcn_mfma_f32_16x16x32_bf16(kf0, qf0, a, 0, 0, 0);
      bf16x8 kf1 = *(const bf16x8*)(Kbs + tb(rt * 16 + lrow, 32 + lg * 8));
      a = __builtin_amdgcn_mfma_f32_16x16x32_bf16(kf1, qf1, a, 0, 0, 0);
      sacc[rt] = a;
    }
    __builtin_amdgcn_s_setprio(0);
    float p[16];
#pragma unroll
    for (int rt = 0; rt < 4; ++rt)
#pragma unroll
      for (int r = 0; r < 4; ++r) {
        float e = __builtin_amdgcn_exp2f(sacc[rt][r]);
        if (diag && (rt * 16 + lg * 4 + r) > tl) e = 0.f;
        p[rt * 4 + r] = e;
      }
    float t0 = (p[0] + p[1]) + (p[2] + p[3]);
    float t1 = (p[4] + p[5]) + (p[6] + p[7]);
    float t2 = (p[8] + p[9]) + (p[10] + p[11]);
    float t3 = (p[12] + p[13]) + (p[14] + p[15]);
    l += (t0 + t1) + (t2 + t3);            // lane-local; reduced in epilogue
#pragma unroll
    for (int rt = 0; rt < 4; ++rt) {
      bf16x4 pk;
#pragma unroll
      for (int r = 0; r < 4; ++r) pk[r] = (bf16)p[rt * 4 + r];
      *(bf16x4*)(pws + tb(lrow, rt * 16 + lg * 4)) = pk;
    }
    __builtin_amdgcn_s_setprio(1);
#pragma unroll
    for (int ks = 0; ks < 2; ++ks) {
      bf16x8 pf = *(const bf16x8*)(pws + tb(lrow, ks * 32 + lg * 8));
      bf16x8 vf0 = *(const bf16x8*)(Vbs + tb(lrow, ks * 32 + lg * 8));
      oa = __builtin_amdgcn_mfma_f32_16x16x32_bf16(vf0, pf, oa, 0, 0, 0);
      bf16x8 vf1 = *(const bf16x8*)(Vbs + tb(16 + lrow, ks * 32 + lg * 8));
      ob = __builtin_amdgcn_mfma_f32_16x16x32_bf16(vf1, pf, ob, 0, 0, 0);
    }
    __builtin_amdgcn_s_setprio(0);
  };

  issue(0, 1 <= qt1);
#pragma unroll 1
  for (int st2 = 0; st2 <= qt1; st2 += 2) {
    const bool has1 = (st2 + 1 <= qt1);
    __syncthreads();                     // prev iter LDS reads done (WAR)
    {
      char* kd = (char*)smem + koff;
      *(bf16x8*)(kd) = s0;
      *(bf16x8*)(kd + 4096) = s1;
      *(bf16x8*)((char*)smem + 16384 + voff) = s4;
      if (has1) {
        *(bf16x8*)(kd + 8192) = s2;
        *(bf16x8*)(kd + 12288) = s3;
        *(bf16x8*)((char*)smem + 20480 + voff) = s5;
      }
    }
    const int nst2 = st2 + 2;
    if (nst2 <= qt1) issue(nst2, nst2 + 1 <= qt1);  // hides under this iter's compute
    __syncthreads();                     // writes visible
    const int nsub = has1 ? 2 : 1;
#pragma unroll 1
    for (int sub = 0; sub < nsub; ++sub) {
      const int stk = st2 + sub;
      const char* Kbs = (const char*)smem + sub * 8192;
      const char* Vbs = (const char*)smem + 16384 + sub * 4096;
      char* pws = (char*)smem + 24576 + w * 2048;
      proc(qB0, qB1, l1, o1a, o1b, Kbs, Vbs, pws, stk == qt1);
      if (stk <= qt0)
        proc(qA0, qA1, l0, o0a, o0b, Kbs, Vbs, pws, stk == qt0);
    }
  }

  auto epi = [&](int tg, float lpart, f32x4 oa, f32x4 ob) {
    float lt = lpart;                      // deferred cross-lane reduce (once)
    lt += __shfl_xor(lt, 16);
    lt += __shfl_xor(lt, 32);
    const float inv = 1.0f / lt;
    const int ntt = tg >> 7, row = tg & 127;
#pragma unroll
    for (int dt = 0; dt < 2; ++dt) {
      const f32x4 v = dt ? ob : oa;
      const int c = h * 32 + dt * 16 + lg * 4;
      char* tile = attTt + (((size_t)(n * 8 + ntt)) * 4 + (c >> 6)) * 16384;
      bf16x4 pk;
#pragma unroll
      for (int r = 0; r < 4; ++r) pk[r] = (bf16)(v[r] * inv);
      *(bf16x4*)(tile + tb(row, c & 63)) = pk;
    }
  };
  epi(tg0, l0, o0a, o0b);
  epi(tg1, l1, o1a, o1b);
}

// ---------------- kernel 3: output projection (64x64, BK=64, T14 reg-staged) ----------------
__global__ __launch_bounds__(256) void k_proj(const char* __restrict__ attTt,
    const char* __restrict__ Wot, const float* __restrict__ bo, float* __restrict__ out) {
  __shared__ __attribute__((aligned(128))) unsigned char smem[16384]; // A 8K | B 8K
  const int tid = threadIdx.x;
  const int tm = blockIdx.x, om = blockIdx.y, n = blockIdx.z;
  const int w = tid >> 6, lane = tid & 63, lrow = lane & 15, lg = lane >> 4;
  const int wm = (w >> 1) * 32, wn = (w & 1) * 32;
  const char* gA = attTt + ((size_t)(n * 8 + (tm >> 1))) * 65536 + (tm & 1) * 8192;
  const char* gB = Wot + (size_t)(om >> 1) * 65536 + (om & 1) * 8192;
  const int coff = w * 1024 + lane * 16;

  bf16x8 pA0, pA1, pB0, pB1;
  auto issue = [&](int kk) {
    const char* a = gA + kk * 16384 + coff;
    pA0 = *(const bf16x8*)(a); pA1 = *(const bf16x8*)(a + 4096);
    const char* bsrc = gB + kk * 16384 + coff;
    pB0 = *(const bf16x8*)(bsrc); pB1 = *(const bf16x8*)(bsrc + 4096);
  };

  f32x4 acc[2][2] = {};
  issue(0);
#pragma unroll 1
  for (int kk = 0; kk < 4; ++kk) {
    __syncthreads();
    char* da = (char*)smem + coff;
    *(bf16x8*)(da) = pA0; *(bf16x8*)(da + 4096) = pA1;
    char* db = (char*)smem + 8192 + coff;
    *(bf16x8*)(db) = pB0; *(bf16x8*)(db + 4096) = pB1;
    if (kk < 3) issue(kk + 1);
    __syncthreads();
    const char* As = (const char*)smem;
    const char* Bs = As + 8192;
    bf16x8 af[2][2], bv[2][2];
#pragma unroll
    for (int mi = 0; mi < 2; ++mi)
#pragma unroll
      for (int kh = 0; kh < 2; ++kh)
        af[mi][kh] = *(const bf16x8*)(As + tb(wm + mi * 16 + lrow, kh * 32 + lg * 8));
#pragma unroll
    for (int ni = 0; ni < 2; ++ni)
#pragma unroll
      for (int kh = 0; kh < 2; ++kh)
        bv[ni][kh] = *(const bf16x8*)(Bs + tb(wn + ni * 16 + lrow, kh * 32 + lg * 8));
#pragma unroll
    for (int kh = 0; kh < 2; ++kh)
#pragma unroll
      for (int mi = 0; mi < 2; ++mi)
#pragma unroll
        for (int ni = 0; ni < 2; ++ni)
          acc[mi][ni] = __builtin_amdgcn_mfma_f32_16x16x32_bf16(af[mi][kh], bv[ni][kh], acc[mi][ni], 0, 0, 0);
  }

  const int t0b = tm * 64 + wm + lg * 4;
  const int ob = om * 64 + wn + lrow;
#pragma unroll
  for (int mi = 0; mi < 2; ++mi) {
    const int t0 = t0b + mi * 16;
#pragma unroll
    for (int ni = 0; ni < 2; ++ni) {
      const int o = ob + ni * 16;
      const float bb = bo[o];
      f32x4 v = acc[mi][ni];
      v[0] += bb; v[1] += bb; v[2] += bb; v[3] += bb;
      *(f32x4*)(out + ((size_t)(n * C_DIM + o)) * T_DIM + t0) = v;
    }
  }
}

extern "C" void kernel_launch(void* const* d_in, const int* in_sizes, int n_in,
                              void* d_out, int out_size, void* d_ws, size_t ws_size,
                              hipStream_t stream) {
  const float* x   = (const float*)d_in[0];
  const float* Wq  = (const float*)d_in[1];
  const float* bq  = (const float*)d_in[2];
  const float* Wkv = (const float*)d_in[3];
  const float* bkv = (const float*)d_in[4];
  const float* Wo  = (const float*)d_in[5];
  const float* bo  = (const float*)d_in[6];
  float* out = (float*)d_out;

  char* ws = (char*)d_ws;
  char* xTt   = ws;                      // 4 MB   [8][8][4][16KB]
  char* Wbt   = ws + (4u  << 20);        // 640 KB [10][4][16KB]
  char* Wot   = ws + (5u  << 20);        // 128 KB [2][4][16KB]
  bf16* q_ws  = (bf16*)(ws + (6u << 20)); // 8 MB  [64][1024][64]
  char* Kt    = ws + (14u << 20);        // 8 MB   [64][16][8KB]
  char* Vt    = ws + (22u << 20);        // 4 MB   [64][16][4KB]
  char* attTt = ws + (26u << 20);        // 4 MB   [8][8][4][16KB]

  k_prep<<<536, 256, 0, stream>>>(x, Wq, Wkv, Wo, xTt, Wbt, Wot);
  k_qkv<<<dim3(8, 10, 8), 256, 0, stream>>>(Wbt, xTt, bq, bkv, q_ws, Kt, Vt);
  k_attn<<<dim3(64, 8), 256, 0, stream>>>(q_ws, Kt, Vt, attTt);
  k_proj<<<dim3(16, 4, 8), 256, 0, stream>>>(attTt, Wot, bo, out);
}